// Round 1
// baseline (1181.409 us; speedup 1.0000x reference)
//
#include <hip/hip_runtime.h>
#include <stdint.h>

#define DMODEL 1024
#define NHEADS 16
#define DK     64
#define BATCH  4
#define SEQ    2048
#define MROWS  (BATCH*SEQ)   // 8192

typedef __bf16 bf16x8 __attribute__((ext_vector_type(8)));
typedef float  f32x4  __attribute__((ext_vector_type(4)));

__device__ __forceinline__ unsigned short f2bf(float f) {
    unsigned int u = __builtin_bit_cast(unsigned int, f);
    u += 0x7fffu + ((u >> 16) & 1u);   // round-to-nearest-even
    return (unsigned short)(u >> 16);
}

// ---------------- fp32 -> bf16 cast, 4 elems/thread ----------------
__global__ void cvt_kernel(const float* __restrict__ src,
                           unsigned short* __restrict__ dst, int n4) {
    int i = blockIdx.x * blockDim.x + threadIdx.x;
    if (i >= n4) return;
    const float4 v = reinterpret_cast<const float4*>(src)[i];
    ushort4 o;
    o.x = f2bf(v.x); o.y = f2bf(v.y); o.z = f2bf(v.z); o.w = f2bf(v.w);
    reinterpret_cast<ushort4*>(dst)[i] = o;
}

// ---------------- GEMM: C[M,N] = A[M,K] * W[N,K]^T + bias ----------------
// MODE 0: bf16 scatter to [B, H, L, DK]   (Q / K)
// MODE 1: bf16 scatter to [B, H, DK, L]   (V transposed)
// MODE 2: fp32 row-major [M, N]           (final output)
template<int MODE>
__global__ __launch_bounds__(256) void gemm_bt(
        const unsigned short* __restrict__ A,
        const unsigned short* __restrict__ W,
        const float* __restrict__ bias,
        void* __restrict__ out,
        int M, int N, int K) {
    const int lane = threadIdx.x & 63;
    const int wave = threadIdx.x >> 6;
    const int quad = lane >> 4;
    const int r15  = lane & 15;
    const int n0 = blockIdx.x * 64;
    const int m0 = blockIdx.y * 64 + wave * 16;

    f32x4 acc[4] = {};
    const unsigned short* Arow = A + (size_t)(m0 + r15) * K + quad * 8;
    const unsigned short* Wrow = W + (size_t)(n0 + r15) * K + quad * 8;

    for (int kk = 0; kk < K; kk += 32) {
        bf16x8 a = *(const bf16x8*)(Arow + kk);
        #pragma unroll
        for (int nt = 0; nt < 4; ++nt) {
            bf16x8 b = *(const bf16x8*)(Wrow + (size_t)nt * 16 * K + kk);
            acc[nt] = __builtin_amdgcn_mfma_f32_16x16x32_bf16(a, b, acc[nt], 0, 0, 0);
        }
    }

    #pragma unroll
    for (int nt = 0; nt < 4; ++nt) {
        #pragma unroll
        for (int r = 0; r < 4; ++r) {
            const int row = m0 + quad * 4 + r;       // C/D: row = quad*4+reg
            const int col = n0 + nt * 16 + r15;      // C/D: col = lane&15
            const float v = acc[nt][r] + bias[col];
            if (MODE == 2) {
                ((float*)out)[(size_t)row * N + col] = v;
            } else {
                const int b = row >> 11, l = row & (SEQ - 1);
                const int h = col >> 6,  d = col & (DK - 1);
                size_t idx;
                if (MODE == 0) idx = (((size_t)(b * NHEADS + h) * SEQ) + l) * DK + d;
                else           idx = (((size_t)(b * NHEADS + h) * DK) + d) * SEQ + l;
                ((unsigned short*)out)[idx] = f2bf(v);
            }
        }
    }
}

// ---------------- Flash attention ----------------
// Q,K: [B,H,L,DK] bf16; Vt: [B,H,DK,L] bf16; mask: [B,L] int32
// Out: bf16 [B, L, DMODEL] with col = h*DK + dv  (ready for Wo GEMM)
__global__ __launch_bounds__(256) void flash_attn(
        const unsigned short* __restrict__ Q,
        const unsigned short* __restrict__ Km,
        const unsigned short* __restrict__ Vt,
        const int* __restrict__ mask,
        unsigned short* __restrict__ Oa) {
    __shared__ __align__(16) unsigned short Pl[4][16][32];
    const int lane = threadIdx.x & 63;
    const int wave = threadIdx.x >> 6;
    const int quad = lane >> 4;
    const int r15  = lane & 15;
    const int bh = blockIdx.y;
    const int b = bh >> 4, h = bh & (NHEADS - 1);
    const int q0 = blockIdx.x * 64 + wave * 16;

    const unsigned short* Qb = Q  + (size_t)bh * SEQ * DK;
    const unsigned short* Kb = Km + (size_t)bh * SEQ * DK;
    const unsigned short* Vb = Vt + (size_t)bh * DK * SEQ;
    const int* mb = mask + b * SEQ;

    // Q fragments for this wave's 16 rows (A layout: m=lane&15, k=quad*8+j)
    const bf16x8 aq0 = *(const bf16x8*)(Qb + (size_t)(q0 + r15) * DK + quad * 8);
    const bf16x8 aq1 = *(const bf16x8*)(Qb + (size_t)(q0 + r15) * DK + 32 + quad * 8);

    float m_run[4], l_run[4];
    f32x4 oacc[4] = {};
    #pragma unroll
    for (int r = 0; r < 4; ++r) { m_run[r] = -1e30f; l_run[r] = 0.f; }

    for (int kb = 0; kb < SEQ; kb += 32) {
        // S = Q K^T for 16 queries x 32 keys
        f32x4 s[2];
        #pragma unroll
        for (int t = 0; t < 2; ++t) {
            const size_t krow = (size_t)(kb + t * 16 + r15) * DK;
            bf16x8 bk0 = *(const bf16x8*)(Kb + krow + quad * 8);
            bf16x8 bk1 = *(const bf16x8*)(Kb + krow + 32 + quad * 8);
            f32x4 z = {};
            z = __builtin_amdgcn_mfma_f32_16x16x32_bf16(aq0, bk0, z, 0, 0, 0);
            z = __builtin_amdgcn_mfma_f32_16x16x32_bf16(aq1, bk1, z, 0, 0, 0);
            s[t] = z;
        }
        const int mk0 = mb[kb + r15];
        const int mk1 = mb[kb + 16 + r15];

        float alpha[4];
        #pragma unroll
        for (int r = 0; r < 4; ++r) {
            float s0 = s[0][r] * 0.125f;     // 1/sqrt(64)
            float s1 = s[1][r] * 0.125f;
            if (mk0 == 0) s0 = -1e9f;
            if (mk1 == 0) s1 = -1e9f;
            float v = fmaxf(s0, s1);         // row max across 16 lanes of this quad
            v = fmaxf(v, __shfl_xor(v, 1));
            v = fmaxf(v, __shfl_xor(v, 2));
            v = fmaxf(v, __shfl_xor(v, 4));
            v = fmaxf(v, __shfl_xor(v, 8));
            const float mnew = fmaxf(m_run[r], v);
            alpha[r] = __expf(m_run[r] - mnew);
            const float p0 = __expf(s0 - mnew);
            const float p1 = __expf(s1 - mnew);
            float su = p0 + p1;
            su += __shfl_xor(su, 1);
            su += __shfl_xor(su, 2);
            su += __shfl_xor(su, 4);
            su += __shfl_xor(su, 8);
            l_run[r] = l_run[r] * alpha[r] + su;
            m_run[r] = mnew;
            // C layout (row=quad*4+r, col=lane&15) -> LDS row-major P[m][k]
            Pl[wave][quad * 4 + r][r15]      = f2bf(p0);
            Pl[wave][quad * 4 + r][16 + r15] = f2bf(p1);
        }
        asm volatile("s_waitcnt lgkmcnt(0)" ::: "memory");
        // reread as A fragment: m=lane&15, k=quad*8+j
        const bf16x8 ap = *(const bf16x8*)(&Pl[wave][r15][quad * 8]);

        #pragma unroll
        for (int nt = 0; nt < 4; ++nt) {
            // B frag from Vt: n=dv=nt*16+lane&15, k=key=kb+quad*8+j (contiguous)
            bf16x8 bv = *(const bf16x8*)(Vb + (size_t)(nt * 16 + r15) * SEQ + kb + quad * 8);
            f32x4 o = oacc[nt];
            #pragma unroll
            for (int r = 0; r < 4; ++r) o[r] *= alpha[r];
            oacc[nt] = __builtin_amdgcn_mfma_f32_16x16x32_bf16(ap, bv, o, 0, 0, 0);
        }
        asm volatile("" ::: "memory");
    }

    #pragma unroll
    for (int nt = 0; nt < 4; ++nt) {
        #pragma unroll
        for (int r = 0; r < 4; ++r) {
            const int row = q0 + quad * 4 + r;
            const int col = h * DK + nt * 16 + r15;
            const float v = oacc[nt][r] / l_run[r];
            Oa[((size_t)b * SEQ + row) * DMODEL + col] = f2bf(v);
        }
    }
}

extern "C" void kernel_launch(void* const* d_in, const int* in_sizes, int n_in,
                              void* d_out, int out_size, void* d_ws, size_t ws_size,
                              hipStream_t stream) {
    (void)in_sizes; (void)n_in; (void)out_size; (void)ws_size;
    const float* x  = (const float*)d_in[0];
    const int* mask = (const int*)d_in[1];
    const float* Wq = (const float*)d_in[2];
    const float* bq = (const float*)d_in[3];
    const float* Wk = (const float*)d_in[4];
    const float* bk = (const float*)d_in[5];
    const float* Wv = (const float*)d_in[6];
    const float* bv = (const float*)d_in[7];
    const float* Wo = (const float*)d_in[8];
    const float* bo = (const float*)d_in[9];
    float* out = (float*)d_out;

    char* ws = (char*)d_ws;
    unsigned short* xb  = (unsigned short*)(ws);                                   // 8192x1024 bf16
    unsigned short* wqb = (unsigned short*)(ws + 16777216);                        // 1024x1024 bf16
    unsigned short* wkb = (unsigned short*)(ws + 16777216 + 1 * 2097152);
    unsigned short* wvb = (unsigned short*)(ws + 16777216 + 2 * 2097152);
    unsigned short* wob = (unsigned short*)(ws + 16777216 + 3 * 2097152);
    unsigned short* qb  = (unsigned short*)(ws + 16777216 + 4 * 2097152);          // [B,H,L,DK]
    unsigned short* kb  = qb  + (size_t)MROWS * DMODEL;                            // [B,H,L,DK]
    unsigned short* vtb = kb  + (size_t)MROWS * DMODEL;                            // [B,H,DK,L]
    unsigned short* ab  = vtb + (size_t)MROWS * DMODEL;                            // [B,L,DMODEL]

    cvt_kernel<<<dim3(MROWS * DMODEL / 4 / 256), 256, 0, stream>>>(x,  xb,  MROWS * DMODEL / 4);
    cvt_kernel<<<dim3(DMODEL * DMODEL / 4 / 256), 256, 0, stream>>>(Wq, wqb, DMODEL * DMODEL / 4);
    cvt_kernel<<<dim3(DMODEL * DMODEL / 4 / 256), 256, 0, stream>>>(Wk, wkb, DMODEL * DMODEL / 4);
    cvt_kernel<<<dim3(DMODEL * DMODEL / 4 / 256), 256, 0, stream>>>(Wv, wvb, DMODEL * DMODEL / 4);
    cvt_kernel<<<dim3(DMODEL * DMODEL / 4 / 256), 256, 0, stream>>>(Wo, wob, DMODEL * DMODEL / 4);

    dim3 g(DMODEL / 64, MROWS / 64), blk(256);
    gemm_bt<0><<<g, blk, 0, stream>>>(xb, wqb, bq, qb,  MROWS, DMODEL, DMODEL);
    gemm_bt<0><<<g, blk, 0, stream>>>(xb, wkb, bk, kb,  MROWS, DMODEL, DMODEL);
    gemm_bt<1><<<g, blk, 0, stream>>>(xb, wvb, bv, vtb, MROWS, DMODEL, DMODEL);

    flash_attn<<<dim3(SEQ / 64, BATCH * NHEADS), blk, 0, stream>>>(qb, kb, vtb, mask, ab);

    gemm_bt<2><<<g, blk, 0, stream>>>(ab, wob, bo, out, MROWS, DMODEL, DMODEL);
}

// Round 2
// 1119.379 us; speedup vs baseline: 1.0554x; 1.0554x over previous
//
#include <hip/hip_runtime.h>
#include <stdint.h>

#define DMODEL 1024
#define NHEADS 16
#define DK     64
#define BATCH  4
#define SEQ    2048
#define MROWS  (BATCH*SEQ)   // 8192

typedef __bf16 bf16x8 __attribute__((ext_vector_type(8)));
typedef float  f32x4  __attribute__((ext_vector_type(4)));

__device__ __forceinline__ unsigned short f2bf(float f) {
    unsigned int u = __builtin_bit_cast(unsigned int, f);
    u += 0x7fffu + ((u >> 16) & 1u);   // round-to-nearest-even
    return (unsigned short)(u >> 16);
}

// ---------------- fp32 -> bf16 cast, 4 elems/thread ----------------
__global__ void cvt_kernel(const float* __restrict__ src,
                           unsigned short* __restrict__ dst, int n4) {
    int i = blockIdx.x * blockDim.x + threadIdx.x;
    if (i >= n4) return;
    const float4 v = reinterpret_cast<const float4*>(src)[i];
    ushort4 o;
    o.x = f2bf(v.x); o.y = f2bf(v.y); o.z = f2bf(v.z); o.w = f2bf(v.w);
    reinterpret_cast<ushort4*>(dst)[i] = o;
}

// ---------------- Fused QKV GEMM ----------------
// A[M,K] * W{q,k,v}[N,K]^T + bias -> Q,K scatter [B,H,L,DK]; V scatter [B,H,DK,L]
__global__ __launch_bounds__(256) void gemm_qkv(
        const unsigned short* __restrict__ A,
        const unsigned short* __restrict__ Wq,
        const unsigned short* __restrict__ Wk,
        const unsigned short* __restrict__ Wv,
        const float* __restrict__ bq,
        const float* __restrict__ bk,
        const float* __restrict__ bv,
        unsigned short* __restrict__ Qo,
        unsigned short* __restrict__ Ko,
        unsigned short* __restrict__ Vo) {
    const int lane = threadIdx.x & 63;
    const int wave = threadIdx.x >> 6;
    const int quad = lane >> 4;
    const int r15  = lane & 15;
    const int n0 = blockIdx.x * 64;
    const int m0 = blockIdx.y * 64 + wave * 16;

    f32x4 acc[3][4] = {};
    const unsigned short* Arow = A + (size_t)(m0 + r15) * DMODEL + quad * 8;
    const unsigned short* Wr0 = Wq + (size_t)(n0 + r15) * DMODEL + quad * 8;
    const unsigned short* Wr1 = Wk + (size_t)(n0 + r15) * DMODEL + quad * 8;
    const unsigned short* Wr2 = Wv + (size_t)(n0 + r15) * DMODEL + quad * 8;

    for (int kk = 0; kk < DMODEL; kk += 32) {
        const bf16x8 a = *(const bf16x8*)(Arow + kk);
        #pragma unroll
        for (int nt = 0; nt < 4; ++nt) {
            const size_t off = (size_t)nt * 16 * DMODEL + kk;
            bf16x8 b0 = *(const bf16x8*)(Wr0 + off);
            bf16x8 b1 = *(const bf16x8*)(Wr1 + off);
            bf16x8 b2 = *(const bf16x8*)(Wr2 + off);
            acc[0][nt] = __builtin_amdgcn_mfma_f32_16x16x32_bf16(a, b0, acc[0][nt], 0, 0, 0);
            acc[1][nt] = __builtin_amdgcn_mfma_f32_16x16x32_bf16(a, b1, acc[1][nt], 0, 0, 0);
            acc[2][nt] = __builtin_amdgcn_mfma_f32_16x16x32_bf16(a, b2, acc[2][nt], 0, 0, 0);
        }
    }

    const float* biases[3] = {bq, bk, bv};
    unsigned short* outs[3] = {Qo, Ko, Vo};
    #pragma unroll
    for (int w = 0; w < 3; ++w) {
        #pragma unroll
        for (int nt = 0; nt < 4; ++nt) {
            #pragma unroll
            for (int r = 0; r < 4; ++r) {
                const int row = m0 + quad * 4 + r;      // C/D: row = quad*4+reg
                const int col = n0 + nt * 16 + r15;     // C/D: col = lane&15
                const float v = acc[w][nt][r] + biases[w][col];
                const int b = row >> 11, l = row & (SEQ - 1);
                const int h = col >> 6,  d = col & (DK - 1);
                size_t idx;
                if (w < 2) idx = (((size_t)(b * NHEADS + h) * SEQ) + l) * DK + d;
                else       idx = (((size_t)(b * NHEADS + h) * DK) + d) * SEQ + l;
                outs[w][idx] = f2bf(v);
            }
        }
    }
}

// ---------------- Final GEMM: out[M,N] = A[M,K] * Wo[N,K]^T + bo (fp32) ------
__global__ __launch_bounds__(256) void gemm_out(
        const unsigned short* __restrict__ A,
        const unsigned short* __restrict__ W,
        const float* __restrict__ bias,
        float* __restrict__ out) {
    const int lane = threadIdx.x & 63;
    const int wave = threadIdx.x >> 6;
    const int quad = lane >> 4;
    const int r15  = lane & 15;
    const int n0 = blockIdx.x * 64;
    const int m0 = blockIdx.y * 64 + wave * 16;

    f32x4 acc[4] = {};
    const unsigned short* Arow = A + (size_t)(m0 + r15) * DMODEL + quad * 8;
    const unsigned short* Wrow = W + (size_t)(n0 + r15) * DMODEL + quad * 8;

    for (int kk = 0; kk < DMODEL; kk += 32) {
        const bf16x8 a = *(const bf16x8*)(Arow + kk);
        #pragma unroll
        for (int nt = 0; nt < 4; ++nt) {
            bf16x8 b = *(const bf16x8*)(Wrow + (size_t)nt * 16 * DMODEL + kk);
            acc[nt] = __builtin_amdgcn_mfma_f32_16x16x32_bf16(a, b, acc[nt], 0, 0, 0);
        }
    }
    #pragma unroll
    for (int nt = 0; nt < 4; ++nt) {
        #pragma unroll
        for (int r = 0; r < 4; ++r) {
            const int row = m0 + quad * 4 + r;
            const int col = n0 + nt * 16 + r15;
            out[(size_t)row * DMODEL + col] = acc[nt][r] + bias[col];
        }
    }
}

// ---------------- Flash attention (fixed-max softmax, S^T trick) ----------
// Q,K: [B,H,L,DK] bf16; Vt: [B,H,DK,L] bf16; mask: [B,L] int32
// Out: bf16 [B, L, DMODEL] with col = h*DK + dv  (ready for Wo GEMM)
__global__ __launch_bounds__(256) void flash_attn(
        const unsigned short* __restrict__ Q,
        const unsigned short* __restrict__ Km,
        const unsigned short* __restrict__ Vt,
        const int* __restrict__ mask,
        unsigned short* __restrict__ Oa) {
    __shared__ __align__(16) unsigned short Pl[4][16][72];  // +8 pad: kills write conflicts
    const int lane = threadIdx.x & 63;
    const int wave = threadIdx.x >> 6;
    const int quad = lane >> 4;
    const int r15  = lane & 15;
    const int bh = blockIdx.y;
    const int b = bh >> 4, h = bh & (NHEADS - 1);
    const int q0 = blockIdx.x * 64 + wave * 16;

    const unsigned short* Qb = Q  + (size_t)bh * SEQ * DK;
    const unsigned short* Kb = Km + (size_t)bh * SEQ * DK;
    const unsigned short* Vb = Vt + (size_t)bh * DK * SEQ;
    const int* mb = mask + b * SEQ;

    // Q fragments (used as the B operand of the S^T MFMA: n=lane&15, k=quad*8+j)
    const bf16x8 bq0 = *(const bf16x8*)(Qb + (size_t)(q0 + r15) * DK + quad * 8);
    const bf16x8 bq1 = *(const bf16x8*)(Qb + (size_t)(q0 + r15) * DK + 32 + quad * 8);

    float l_part = 0.f;
    f32x4 oacc[4] = {};

    for (int kb = 0; kb < SEQ; kb += 64) {
        uint2 pw[4];
        #pragma unroll
        for (int t = 0; t < 4; ++t) {
            const size_t krow = (size_t)(kb + t * 16 + r15) * DK;
            const bf16x8 ak0 = *(const bf16x8*)(Kb + krow + quad * 8);
            const bf16x8 ak1 = *(const bf16x8*)(Kb + krow + 32 + quad * 8);
            f32x4 z = {};
            z = __builtin_amdgcn_mfma_f32_16x16x32_bf16(ak0, bq0, z, 0, 0, 0);
            z = __builtin_amdgcn_mfma_f32_16x16x32_bf16(ak1, bq1, z, 0, 0, 0);
            // z = S^T tile: lane holds (key_local = quad*4+r, query = r15)
            const int4 m4 = *(const int4*)(mb + kb + t * 16 + quad * 4);
            float p[4];
            #pragma unroll
            for (int r = 0; r < 4; ++r) {
                const int mk = (r == 0) ? m4.x : (r == 1) ? m4.y : (r == 2) ? m4.z : m4.w;
                const float sv = z[r] * 0.125f + (mk == 0 ? -1e9f : 0.f);
                p[r] = __expf(fminf(sv, 60.f));  // masked -> exp(-1e9) == 0
                l_part += p[r];
            }
            pw[t].x = (uint)f2bf(p[0]) | ((uint)f2bf(p[1]) << 16);
            pw[t].y = (uint)f2bf(p[2]) | ((uint)f2bf(p[3]) << 16);
        }
        // P[query][key] row-major: lane writes 4 consecutive keys -> one b64 each
        #pragma unroll
        for (int t = 0; t < 4; ++t)
            *(uint2*)(&Pl[wave][r15][t * 16 + quad * 4]) = pw[t];

        asm volatile("s_waitcnt lgkmcnt(0)" ::: "memory");
        const bf16x8 ap0 = *(const bf16x8*)(&Pl[wave][r15][quad * 8]);
        const bf16x8 ap1 = *(const bf16x8*)(&Pl[wave][r15][32 + quad * 8]);

        #pragma unroll
        for (int nt = 0; nt < 4; ++nt) {
            const unsigned short* vrow = Vb + (size_t)(nt * 16 + r15) * SEQ + kb;
            const bf16x8 bv0 = *(const bf16x8*)(vrow + quad * 8);
            const bf16x8 bv1 = *(const bf16x8*)(vrow + 32 + quad * 8);
            oacc[nt] = __builtin_amdgcn_mfma_f32_16x16x32_bf16(ap0, bv0, oacc[nt], 0, 0, 0);
            oacc[nt] = __builtin_amdgcn_mfma_f32_16x16x32_bf16(ap1, bv1, oacc[nt], 0, 0, 0);
        }
    }

    // l reduction: l_part covers this lane's keys for query r15; sum over quads
    float l = l_part;
    l += __shfl_xor(l, 16);
    l += __shfl_xor(l, 32);   // every lane: l for query index r15
    float lq[4];
    #pragma unroll
    for (int r = 0; r < 4; ++r) lq[r] = __shfl(l, quad * 4 + r, 64);

    #pragma unroll
    for (int nt = 0; nt < 4; ++nt) {
        #pragma unroll
        for (int r = 0; r < 4; ++r) {
            const int row = q0 + quad * 4 + r;
            const int col = h * DK + nt * 16 + r15;
            const float v = oacc[nt][r] / lq[r];
            Oa[((size_t)b * SEQ + row) * DMODEL + col] = f2bf(v);
        }
    }
}

extern "C" void kernel_launch(void* const* d_in, const int* in_sizes, int n_in,
                              void* d_out, int out_size, void* d_ws, size_t ws_size,
                              hipStream_t stream) {
    (void)in_sizes; (void)n_in; (void)out_size; (void)ws_size;
    const float* x  = (const float*)d_in[0];
    const int* mask = (const int*)d_in[1];
    const float* Wq = (const float*)d_in[2];
    const float* bq = (const float*)d_in[3];
    const float* Wk = (const float*)d_in[4];
    const float* bk = (const float*)d_in[5];
    const float* Wv = (const float*)d_in[6];
    const float* bv = (const float*)d_in[7];
    const float* Wo = (const float*)d_in[8];
    const float* bo = (const float*)d_in[9];
    float* out = (float*)d_out;

    char* ws = (char*)d_ws;
    unsigned short* xb  = (unsigned short*)(ws);                                   // 8192x1024 bf16
    unsigned short* wqb = (unsigned short*)(ws + 16777216);                        // 1024x1024 bf16
    unsigned short* wkb = (unsigned short*)(ws + 16777216 + 1 * 2097152);
    unsigned short* wvb = (unsigned short*)(ws + 16777216 + 2 * 2097152);
    unsigned short* wob = (unsigned short*)(ws + 16777216 + 3 * 2097152);
    unsigned short* qb  = (unsigned short*)(ws + 16777216 + 4 * 2097152);          // [B,H,L,DK]
    unsigned short* kb  = qb  + (size_t)MROWS * DMODEL;                            // [B,H,L,DK]
    unsigned short* vtb = kb  + (size_t)MROWS * DMODEL;                            // [B,H,DK,L]
    unsigned short* ab  = vtb + (size_t)MROWS * DMODEL;                            // [B,L,DMODEL]

    cvt_kernel<<<dim3(MROWS * DMODEL / 4 / 256), 256, 0, stream>>>(x,  xb,  MROWS * DMODEL / 4);
    cvt_kernel<<<dim3(DMODEL * DMODEL / 4 / 256), 256, 0, stream>>>(Wq, wqb, DMODEL * DMODEL / 4);
    cvt_kernel<<<dim3(DMODEL * DMODEL / 4 / 256), 256, 0, stream>>>(Wk, wkb, DMODEL * DMODEL / 4);
    cvt_kernel<<<dim3(DMODEL * DMODEL / 4 / 256), 256, 0, stream>>>(Wv, wvb, DMODEL * DMODEL / 4);
    cvt_kernel<<<dim3(DMODEL * DMODEL / 4 / 256), 256, 0, stream>>>(Wo, wob, DMODEL * DMODEL / 4);

    dim3 g(DMODEL / 64, MROWS / 64), blk(256);
    gemm_qkv<<<g, blk, 0, stream>>>(xb, wqb, wkb, wvb, bq, bk, bv, qb, kb, vtb);

    flash_attn<<<dim3(SEQ / 64, BATCH * NHEADS), blk, 0, stream>>>(qb, kb, vtb, mask, ab);

    gemm_out<<<g, blk, 0, stream>>>(ab, wob, bo, out);
}

// Round 3
// 345.016 us; speedup vs baseline: 3.4242x; 3.2444x over previous
//
#include <hip/hip_runtime.h>
#include <stdint.h>

#define DMODEL 1024
#define NHEADS 16
#define DK     64
#define BATCH  4
#define SEQ    2048
#define MROWS  (BATCH*SEQ)   // 8192

typedef __bf16 bf16x8 __attribute__((ext_vector_type(8)));
typedef float  f32x4  __attribute__((ext_vector_type(4)));

__device__ __forceinline__ unsigned short f2bf(float f) {
    unsigned int u = __builtin_bit_cast(unsigned int, f);
    u += 0x7fffu + ((u >> 16) & 1u);   // round-to-nearest-even
    return (unsigned short)(u >> 16);
}

// async global->LDS, 16 B per lane, LDS dest = uniform base + lane*16
#define GLDS(gp, lp) __builtin_amdgcn_global_load_lds( \
    (const __attribute__((address_space(1))) unsigned int*)(gp), \
    (__attribute__((address_space(3))) unsigned int*)(lp), 16, 0, 0)

// ---------------- fp32 -> bf16 cast, 4 elems/thread ----------------
__global__ void cvt_kernel(const float* __restrict__ src,
                           unsigned short* __restrict__ dst, int n4) {
    int i = blockIdx.x * blockDim.x + threadIdx.x;
    if (i >= n4) return;
    const float4 v = reinterpret_cast<const float4*>(src)[i];
    ushort4 o;
    o.x = f2bf(v.x); o.y = f2bf(v.y); o.z = f2bf(v.z); o.w = f2bf(v.w);
    reinterpret_cast<ushort4*>(dst)[i] = o;
}

// ---------------- 128x128-tile GEMM, BK=64, LDS staged ----------------
// C[M,N] = A[M,1024] * W[N,1024]^T + bias
// MODE 0: fused QKV. blockIdx.x: 0..23 -> which = x>>3 (0=Q,1=K,2=V), ntile = x&7
//         Q,K scatter -> [BH, L, 64] ; V scatter -> blocked [BH, kblk, dv, 64]
// MODE 1: fp32 row-major out [M, 1024]
template<int MODE>
__global__ __launch_bounds__(256, 3) void gemm128(
        const unsigned short* __restrict__ A,
        const unsigned short* __restrict__ W0,
        const unsigned short* __restrict__ W1,
        const unsigned short* __restrict__ W2,
        const float* __restrict__ b0,
        const float* __restrict__ b1,
        const float* __restrict__ b2,
        void* __restrict__ o0, void* __restrict__ o1, void* __restrict__ o2) {
    __shared__ unsigned short As[128 * 64];   // 16 KB, rows of 64 bf16, chunk-swizzled
    __shared__ unsigned short Bs[128 * 64];   // 16 KB
    const int lane = threadIdx.x & 63;
    const int wave = threadIdx.x >> 6;
    const int quad = lane >> 4;
    const int r15  = lane & 15;
    const int wr = wave >> 1, wc = wave & 1;
    const int m0 = blockIdx.y * 128;

    int which, ncol0;
    const unsigned short* W;
    const float* bias;
    if (MODE == 0) {
        which = blockIdx.x >> 3;
        ncol0 = (blockIdx.x & 7) * 128;
        W    = which == 0 ? W0 : (which == 1 ? W1 : W2);
        bias = which == 0 ? b0 : (which == 1 ? b1 : b2);
    } else {
        which = 0; ncol0 = blockIdx.x * 128; W = W0; bias = b0;
    }

    // staging source addressing: lane covers (row = seg*8 + lane/8, chunk = lane&7),
    // global chunk swizzled by row&7 so LDS stays DMA-contiguous yet reads are conflict-free
    const int srow = lane >> 3;
    const int scg  = (lane & 7) ^ srow;          // row&7 == srow
    const unsigned short* Ag[4];
    const unsigned short* Wg[4];
    #pragma unroll
    for (int j = 0; j < 4; ++j) {
        const int row = (wave * 4 + j) * 8 + srow;
        Ag[j] = A + (m0 + row) * DMODEL + scg * 8;
        Wg[j] = W + (ncol0 + row) * DMODEL + scg * 8;
    }

    f32x4 acc[4][4] = {};
    for (int kk = 0; kk < DMODEL; kk += 64) {
        __syncthreads();
        #pragma unroll
        for (int j = 0; j < 4; ++j) {
            GLDS(Ag[j] + kk, &As[(wave * 4 + j) * 512]);
            GLDS(Wg[j] + kk, &Bs[(wave * 4 + j) * 512]);
        }
        __syncthreads();
        #pragma unroll
        for (int u = 0; u < 2; ++u) {
            bf16x8 af[4], bfx[4];
            const int cs = ((u * 4 + quad) ^ (r15 & 7)) * 8;
            #pragma unroll
            for (int t = 0; t < 4; ++t) {
                af[t]  = *(const bf16x8*)&As[(wr * 64 + t * 16 + r15) * 64 + cs];
                bfx[t] = *(const bf16x8*)&Bs[(wc * 64 + t * 16 + r15) * 64 + cs];
            }
            #pragma unroll
            for (int mt = 0; mt < 4; ++mt)
                #pragma unroll
                for (int nt = 0; nt < 4; ++nt)
                    acc[mt][nt] = __builtin_amdgcn_mfma_f32_16x16x32_bf16(
                        af[mt], bfx[nt], acc[mt][nt], 0, 0, 0);
        }
    }

    // epilogue
    #pragma unroll
    for (int mt = 0; mt < 4; ++mt) {
        #pragma unroll
        for (int nt = 0; nt < 4; ++nt) {
            #pragma unroll
            for (int r = 0; r < 4; ++r) {
                const int row = m0 + wr * 64 + mt * 16 + quad * 4 + r;  // C row = quad*4+reg
                const int col = ncol0 + wc * 64 + nt * 16 + r15;        // C col = lane&15
                const float v = acc[mt][nt][r] + bias[col];
                if (MODE == 1) {
                    ((float*)o0)[(size_t)row * DMODEL + col] = v;
                } else {
                    const int b = row >> 11, l = row & (SEQ - 1);
                    const int h = col >> 6,  d = col & (DK - 1);
                    const int bh = b * NHEADS + h;
                    unsigned short* ow = (unsigned short*)(which == 0 ? o0 : (which == 1 ? o1 : o2));
                    size_t idx;
                    if (which < 2) idx = ((size_t)bh * SEQ + l) * DK + d;
                    else           idx = (size_t)bh * (SEQ * DK) + (l >> 6) * (DK * 64) + d * 64 + (l & 63);
                    ow[idx] = f2bf(v);
                }
            }
        }
    }
}

// ---------------- Flash attention, LDS-staged K/V tiles ----------------
// Q,K: [BH, L, 64] bf16; Vb: blocked [BH, kblk, dv, 64] bf16; mask: [B,L] int32
// Out: bf16 [B, L, DMODEL] with col = h*64 + dv  (feeds Wo GEMM)
__global__ __launch_bounds__(256, 3) void flash_attn(
        const unsigned short* __restrict__ Q,
        const unsigned short* __restrict__ Km,
        const unsigned short* __restrict__ Vm,
        const int* __restrict__ mask,
        unsigned short* __restrict__ Oa) {
    __shared__ unsigned short Ks[64 * 64];        // 8 KB  [key][dk] swizzled
    __shared__ unsigned short Vs[64 * 64];        // 8 KB  [dv][key] swizzled
    __shared__ unsigned short Pl[4][2][16 * 64];  // 16 KB [wave][qf][q][key] swizzled
    const int lane = threadIdx.x & 63;
    const int wave = threadIdx.x >> 6;
    const int quad = lane >> 4;
    const int r15  = lane & 15;

    // XCD-aware remap: each XCD walks one head's 16 q-tiles before moving on
    const int id   = (blockIdx.y << 4) | blockIdx.x;   // gridDim.x == 16
    const int xcd  = id & 7;
    const int slot = id >> 3;                          // 0..127
    const int bh   = xcd + ((slot >> 4) << 3);         // 0..63
    const int qt   = slot & 15;
    const int b = bh >> 4, h = bh & (NHEADS - 1);
    const int q0 = qt * 128 + wave * 32;

    const unsigned short* Qb = Q  + (size_t)bh * SEQ * DK;
    const unsigned short* Kb = Km + (size_t)bh * SEQ * DK;
    const unsigned short* Vb = Vm + (size_t)bh * SEQ * DK;
    const int* mb = mask + b * SEQ;

    const int srow = lane >> 3;
    const int soff = ((lane >> 3) * 64) + (((lane & 7) ^ srow) * 8);  // staging per-lane offset

    // Q fragments (B operand of S^T MFMA): 2 q-frags x 2 k-halves
    bf16x8 bq[2][2];
    #pragma unroll
    for (int qf = 0; qf < 2; ++qf)
        #pragma unroll
        for (int u = 0; u < 2; ++u)
            bq[qf][u] = *(const bf16x8*)(Qb + (q0 + qf * 16 + r15) * DK + u * 32 + quad * 8);

    float l_part[2] = {0.f, 0.f};
    f32x4 oacc[2][4] = {};

    for (int kb = 0; kb < SEQ; kb += 64) {
        __syncthreads();   // all waves done reading previous tiles
        const unsigned short* Kg = Kb + kb * 64;   // 64 rows x 128 B, contiguous
        const unsigned short* Vg = Vb + kb * 64;   // blocked tile, contiguous
        #pragma unroll
        for (int j = 0; j < 2; ++j) {
            const int wseg = wave * 2 + j;
            GLDS(Kg + wseg * 512 + soff, &Ks[wseg * 512]);
            GLDS(Vg + wseg * 512 + soff, &Vs[wseg * 512]);
        }
        __syncthreads();   // compiler drains vmcnt before barrier

        char* const Pb = (char*)&Pl[wave][0][0];
        #pragma unroll
        for (int t = 0; t < 4; ++t) {
            const bf16x8 ak0 = *(const bf16x8*)&Ks[(t * 16 + r15) * 64 + ((quad ^ (r15 & 7)) * 8)];
            const bf16x8 ak1 = *(const bf16x8*)&Ks[(t * 16 + r15) * 64 + (((4 + quad) ^ (r15 & 7)) * 8)];
            const int4 m4 = *(const int4*)(mb + kb + t * 16 + quad * 4);
            #pragma unroll
            for (int qf = 0; qf < 2; ++qf) {
                f32x4 z = {};
                z = __builtin_amdgcn_mfma_f32_16x16x32_bf16(ak0, bq[qf][0], z, 0, 0, 0);
                z = __builtin_amdgcn_mfma_f32_16x16x32_bf16(ak1, bq[qf][1], z, 0, 0, 0);
                // z = S^T: lane holds (key = t*16+quad*4+r, query = r15)
                float p[4];
                #pragma unroll
                for (int r = 0; r < 4; ++r) {
                    const int mk = (r == 0) ? m4.x : (r == 1) ? m4.y : (r == 2) ? m4.z : m4.w;
                    const float sv = z[r] * 0.125f + (mk == 0 ? -1e9f : 0.f);
                    p[r] = __expf(fminf(sv, 60.f));
                    l_part[qf] += p[r];
                }
                uint2 pw;
                pw.x = (uint)f2bf(p[0]) | ((uint)f2bf(p[1]) << 16);
                pw.y = (uint)f2bf(p[2]) | ((uint)f2bf(p[3]) << 16);
                const int c2 = (t * 2 + (quad >> 1)) ^ (r15 & 7);
                *(uint2*)(Pb + qf * 2048 + r15 * 128 + c2 * 16 + (quad & 1) * 8) = pw;
            }
        }
        asm volatile("s_waitcnt lgkmcnt(0)" ::: "memory");

        #pragma unroll
        for (int u = 0; u < 2; ++u) {
            const int cs = ((u * 4 + quad) ^ (r15 & 7)) * 8;
            bf16x8 vf[4];
            #pragma unroll
            for (int nt = 0; nt < 4; ++nt)
                vf[nt] = *(const bf16x8*)&Vs[(nt * 16 + r15) * 64 + cs];
            #pragma unroll
            for (int qf = 0; qf < 2; ++qf) {
                const bf16x8 ap = *(const bf16x8*)(Pb + qf * 2048 + r15 * 128 + cs * 2);
                #pragma unroll
                for (int nt = 0; nt < 4; ++nt)
                    oacc[qf][nt] = __builtin_amdgcn_mfma_f32_16x16x32_bf16(
                        ap, vf[nt], oacc[qf][nt], 0, 0, 0);
            }
        }
    }

    #pragma unroll
    for (int qf = 0; qf < 2; ++qf) {
        float l = l_part[qf];
        l += __shfl_xor(l, 16);
        l += __shfl_xor(l, 32);      // now: l for query r15 (within fragment qf)
        float lq[4];
        #pragma unroll
        for (int r = 0; r < 4; ++r) lq[r] = __shfl(l, quad * 4 + r, 64);
        #pragma unroll
        for (int nt = 0; nt < 4; ++nt) {
            #pragma unroll
            for (int r = 0; r < 4; ++r) {
                const int row = q0 + qf * 16 + quad * 4 + r;
                const int col = h * DK + nt * 16 + r15;
                Oa[((size_t)b * SEQ + row) * DMODEL + col] = f2bf(oacc[qf][nt][r] / lq[r]);
            }
        }
    }
}

extern "C" void kernel_launch(void* const* d_in, const int* in_sizes, int n_in,
                              void* d_out, int out_size, void* d_ws, size_t ws_size,
                              hipStream_t stream) {
    (void)in_sizes; (void)n_in; (void)out_size; (void)ws_size;
    const float* x  = (const float*)d_in[0];
    const int* mask = (const int*)d_in[1];
    const float* Wq = (const float*)d_in[2];
    const float* bq = (const float*)d_in[3];
    const float* Wk = (const float*)d_in[4];
    const float* bk = (const float*)d_in[5];
    const float* Wv = (const float*)d_in[6];
    const float* bv = (const float*)d_in[7];
    const float* Wo = (const float*)d_in[8];
    const float* bo = (const float*)d_in[9];
    float* out = (float*)d_out;

    char* ws = (char*)d_ws;
    unsigned short* xb  = (unsigned short*)(ws);                                   // 8192x1024 bf16
    unsigned short* wqb = (unsigned short*)(ws + 16777216);                        // 1024x1024 bf16
    unsigned short* wkb = (unsigned short*)(ws + 16777216 + 1 * 2097152);
    unsigned short* wvb = (unsigned short*)(ws + 16777216 + 2 * 2097152);
    unsigned short* wob = (unsigned short*)(ws + 16777216 + 3 * 2097152);
    unsigned short* qb  = (unsigned short*)(ws + 16777216 + 4 * 2097152);          // [BH,L,64]
    unsigned short* kb  = qb  + (size_t)MROWS * DMODEL;                            // [BH,L,64]
    unsigned short* vtb = kb  + (size_t)MROWS * DMODEL;                            // blocked V
    unsigned short* ab  = vtb + (size_t)MROWS * DMODEL;                            // [B,L,DMODEL]

    cvt_kernel<<<dim3(MROWS * DMODEL / 4 / 256), 256, 0, stream>>>(x,  xb,  MROWS * DMODEL / 4);
    cvt_kernel<<<dim3(DMODEL * DMODEL / 4 / 256), 256, 0, stream>>>(Wq, wqb, DMODEL * DMODEL / 4);
    cvt_kernel<<<dim3(DMODEL * DMODEL / 4 / 256), 256, 0, stream>>>(Wk, wkb, DMODEL * DMODEL / 4);
    cvt_kernel<<<dim3(DMODEL * DMODEL / 4 / 256), 256, 0, stream>>>(Wv, wvb, DMODEL * DMODEL / 4);
    cvt_kernel<<<dim3(DMODEL * DMODEL / 4 / 256), 256, 0, stream>>>(Wo, wob, DMODEL * DMODEL / 4);

    // fused QKV: grid.x = 3 weights x 8 n-tiles
    gemm128<0><<<dim3(24, MROWS / 128), 256, 0, stream>>>(
        xb, wqb, wkb, wvb, bq, bk, bv, qb, kb, vtb);

    flash_attn<<<dim3(16, BATCH * NHEADS), 256, 0, stream>>>(qb, kb, vtb, mask, ab);

    gemm128<1><<<dim3(8, MROWS / 128), 256, 0, stream>>>(
        ab, wob, nullptr, nullptr, bo, nullptr, nullptr, out, nullptr, nullptr);
}

// Round 4
// 301.275 us; speedup vs baseline: 3.9214x; 1.1452x over previous
//
#include <hip/hip_runtime.h>
#include <stdint.h>

#define DMODEL 1024
#define NHEADS 16
#define DK     64
#define BATCH  4
#define SEQ    2048
#define MROWS  (BATCH*SEQ)   // 8192

typedef __bf16 bf16x8 __attribute__((ext_vector_type(8)));
typedef float  f32x4  __attribute__((ext_vector_type(4)));

#if defined(__has_builtin)
#if __has_builtin(__builtin_amdgcn_exp2f)
#define EXP2F(x) __builtin_amdgcn_exp2f(x)
#endif
#endif
#ifndef EXP2F
#define EXP2F(x) exp2f(x)
#endif

__device__ __forceinline__ unsigned short f2bf(float f) {
    unsigned int u = __builtin_bit_cast(unsigned int, f);
    u += 0x7fffu + ((u >> 16) & 1u);   // round-to-nearest-even
    return (unsigned short)(u >> 16);
}

// pack two f32 -> two bf16 (round-to-nearest) in one v_perm
__device__ __forceinline__ unsigned int pack_bf16(float a, float b) {
    unsigned int ua = __builtin_bit_cast(unsigned int, a) + 0x8000u;
    unsigned int ub = __builtin_bit_cast(unsigned int, b) + 0x8000u;
    return __builtin_amdgcn_perm(ub, ua, 0x07060302u);  // lo16=a.hi16, hi16=b.hi16
}

// async global->LDS, 16 B per lane, LDS dest = uniform base + lane*16
#define GLDS(gp, lp) __builtin_amdgcn_global_load_lds( \
    (const __attribute__((address_space(1))) unsigned int*)(gp), \
    (__attribute__((address_space(3))) unsigned int*)(lp), 16, 0, 0)

// ---------------- fp32 -> bf16 cast, 4 elems/thread ----------------
__global__ void cvt_kernel(const float* __restrict__ src,
                           unsigned short* __restrict__ dst, int n4) {
    int i = blockIdx.x * blockDim.x + threadIdx.x;
    if (i >= n4) return;
    const float4 v = reinterpret_cast<const float4*>(src)[i];
    ushort4 o;
    o.x = f2bf(v.x); o.y = f2bf(v.y); o.z = f2bf(v.z); o.w = f2bf(v.w);
    reinterpret_cast<ushort4*>(dst)[i] = o;
}

// 4 weight matrices (1024x1024 each) in one launch; blockIdx.y selects
__global__ void cvtw_kernel(const float* __restrict__ w0, const float* __restrict__ w1,
                            const float* __restrict__ w2, const float* __restrict__ w3,
                            unsigned short* __restrict__ d0, unsigned short* __restrict__ d1,
                            unsigned short* __restrict__ d2, unsigned short* __restrict__ d3) {
    const float* s; unsigned short* d;
    switch (blockIdx.y) {
        case 0:  s = w0; d = d0; break;
        case 1:  s = w1; d = d1; break;
        case 2:  s = w2; d = d2; break;
        default: s = w3; d = d3; break;
    }
    const int i = blockIdx.x * blockDim.x + threadIdx.x;
    const float4 v = reinterpret_cast<const float4*>(s)[i];
    ushort4 o;
    o.x = f2bf(v.x); o.y = f2bf(v.y); o.z = f2bf(v.z); o.w = f2bf(v.w);
    reinterpret_cast<ushort4*>(d)[i] = o;
}

// mask[B,L] int32 -> float bias (0 or -1e30)
__global__ void maskbias_kernel(const int* __restrict__ m, float* __restrict__ o, int n) {
    const int i = blockIdx.x * blockDim.x + threadIdx.x;
    if (i < n) o[i] = m[i] ? 0.f : -1e30f;
}

// ---------------- 128x128-tile GEMM, BK=64, LDS staged ----------------
// C[M,N] = A[M,1024] * W[N,1024]^T + bias
// MODE 0: fused QKV. blockIdx.x: 0..23 -> which = x>>3 (0=Q,1=K,2=V), ntile = x&7
//         Q scaled by 0.125*log2(e); Q,K scatter -> [BH, L, 64];
//         V scatter -> blocked [BH, kblk, dv, 64]
// MODE 1: fp32 row-major out [M, 1024]
template<int MODE>
__global__ __launch_bounds__(256, 3) void gemm128(
        const unsigned short* __restrict__ A,
        const unsigned short* __restrict__ W0,
        const unsigned short* __restrict__ W1,
        const unsigned short* __restrict__ W2,
        const float* __restrict__ b0,
        const float* __restrict__ b1,
        const float* __restrict__ b2,
        void* __restrict__ o0, void* __restrict__ o1, void* __restrict__ o2) {
    __shared__ unsigned short As[128 * 64];   // 16 KB, rows of 64 bf16, chunk-swizzled
    __shared__ unsigned short Bs[128 * 64];   // 16 KB
    const int lane = threadIdx.x & 63;
    const int wave = threadIdx.x >> 6;
    const int quad = lane >> 4;
    const int r15  = lane & 15;
    const int wr = wave >> 1, wc = wave & 1;
    const int m0 = blockIdx.y * 128;

    int which, ncol0;
    const unsigned short* W;
    const float* bias;
    if (MODE == 0) {
        which = blockIdx.x >> 3;
        ncol0 = (blockIdx.x & 7) * 128;
        W    = which == 0 ? W0 : (which == 1 ? W1 : W2);
        bias = which == 0 ? b0 : (which == 1 ? b1 : b2);
    } else {
        which = 0; ncol0 = blockIdx.x * 128; W = W0; bias = b0;
    }

    // staging: lane covers (row = seg*8 + lane/8, chunk = lane&7),
    // global chunk swizzled by row&7 so LDS stays DMA-contiguous yet reads conflict-free
    const int srow = lane >> 3;
    const int scg  = (lane & 7) ^ srow;
    const unsigned short* Ag[4];
    const unsigned short* Wg[4];
    #pragma unroll
    for (int j = 0; j < 4; ++j) {
        const int row = (wave * 4 + j) * 8 + srow;
        Ag[j] = A + (m0 + row) * DMODEL + scg * 8;
        Wg[j] = W + (ncol0 + row) * DMODEL + scg * 8;
    }

    f32x4 acc[4][4] = {};
    for (int kk = 0; kk < DMODEL; kk += 64) {
        __syncthreads();
        #pragma unroll
        for (int j = 0; j < 4; ++j) {
            GLDS(Ag[j] + kk, &As[(wave * 4 + j) * 512]);
            GLDS(Wg[j] + kk, &Bs[(wave * 4 + j) * 512]);
        }
        __syncthreads();
        #pragma unroll
        for (int u = 0; u < 2; ++u) {
            bf16x8 af[4], bfx[4];
            const int cs = ((u * 4 + quad) ^ (r15 & 7)) * 8;
            #pragma unroll
            for (int t = 0; t < 4; ++t) {
                af[t]  = *(const bf16x8*)&As[(wr * 64 + t * 16 + r15) * 64 + cs];
                bfx[t] = *(const bf16x8*)&Bs[(wc * 64 + t * 16 + r15) * 64 + cs];
            }
            #pragma unroll
            for (int mt = 0; mt < 4; ++mt)
                #pragma unroll
                for (int nt = 0; nt < 4; ++nt)
                    acc[mt][nt] = __builtin_amdgcn_mfma_f32_16x16x32_bf16(
                        af[mt], bfx[nt], acc[mt][nt], 0, 0, 0);
        }
    }

    // epilogue
    #pragma unroll
    for (int mt = 0; mt < 4; ++mt) {
        #pragma unroll
        for (int nt = 0; nt < 4; ++nt) {
            #pragma unroll
            for (int r = 0; r < 4; ++r) {
                const int row = m0 + wr * 64 + mt * 16 + quad * 4 + r;  // C row = quad*4+reg
                const int col = ncol0 + wc * 64 + nt * 16 + r15;        // C col = lane&15
                float v = acc[mt][nt][r] + bias[col];
                if (MODE == 1) {
                    ((float*)o0)[(size_t)row * DMODEL + col] = v;
                } else {
                    if (which == 0) v *= 0.18033688011112042f;  // 0.125*log2(e)
                    const int b = row >> 11, l = row & (SEQ - 1);
                    const int h = col >> 6,  d = col & (DK - 1);
                    const int bh = b * NHEADS + h;
                    unsigned short* ow = (unsigned short*)(which == 0 ? o0 : (which == 1 ? o1 : o2));
                    size_t idx;
                    if (which < 2) idx = ((size_t)bh * SEQ + l) * DK + d;
                    else           idx = (size_t)bh * (SEQ * DK) + (l >> 6) * (DK * 64) + d * 64 + (l & 63);
                    ow[idx] = f2bf(v);
                }
            }
        }
    }
}

// ---------------- Flash attention, LDS-staged K/V tiles ----------------
// Q (pre-scaled by 0.125*log2e), K: [BH, L, 64] bf16; Vb: blocked [BH, kblk, dv, 64];
// mbf: [B,L] float bias (0 / -1e30). Out: bf16 [B, L, DMODEL], col = h*64+dv.
__global__ __launch_bounds__(256, 4) void flash_attn(
        const unsigned short* __restrict__ Q,
        const unsigned short* __restrict__ Km,
        const unsigned short* __restrict__ Vm,
        const float* __restrict__ mbf,
        unsigned short* __restrict__ Oa) {
    __shared__ unsigned short Ks[64 * 64];        // 8 KB  [key][dk] swizzled
    __shared__ unsigned short Vs[64 * 64];        // 8 KB  [dv][key] swizzled
    __shared__ unsigned short Pl[4][2][16 * 64];  // 16 KB [wave][qf][q][key] swizzled
    const int lane = threadIdx.x & 63;
    const int wave = threadIdx.x >> 6;
    const int quad = lane >> 4;
    const int r15  = lane & 15;

    // XCD-aware remap: each XCD walks one head's 16 q-tiles before moving on
    const int id   = (blockIdx.y << 4) | blockIdx.x;   // gridDim.x == 16
    const int xcd  = id & 7;
    const int slot = id >> 3;                          // 0..127
    const int bh   = xcd + ((slot >> 4) << 3);         // 0..63
    const int qt   = slot & 15;
    const int b = bh >> 4, h = bh & (NHEADS - 1);
    const int q0 = qt * 128 + wave * 32;

    const unsigned short* Qb = Q  + (size_t)bh * SEQ * DK;
    const unsigned short* Kb = Km + (size_t)bh * SEQ * DK;
    const unsigned short* Vb = Vm + (size_t)bh * SEQ * DK;
    const float* mb = mbf + b * SEQ;

    const int srow = lane >> 3;
    const int soff = ((lane >> 3) * 64) + (((lane & 7) ^ srow) * 8);

    // Q fragments (B operand of S^T MFMA): 2 q-frags x 2 k-halves
    bf16x8 bq[2][2];
    #pragma unroll
    for (int qf = 0; qf < 2; ++qf)
        #pragma unroll
        for (int u = 0; u < 2; ++u)
            bq[qf][u] = *(const bf16x8*)(Qb + (q0 + qf * 16 + r15) * DK + u * 32 + quad * 8);

    float l_part[2] = {0.f, 0.f};
    f32x4 oacc[2][4] = {};

    for (int kb = 0; kb < SEQ; kb += 64) {
        __syncthreads();   // all waves done reading previous tiles
        const unsigned short* Kg = Kb + kb * 64;   // 64 rows x 128 B, contiguous
        const unsigned short* Vg = Vb + kb * 64;   // blocked tile, contiguous
        #pragma unroll
        for (int j = 0; j < 2; ++j) {
            const int wseg = wave * 2 + j;
            GLDS(Kg + wseg * 512 + soff, &Ks[wseg * 512]);
            GLDS(Vg + wseg * 512 + soff, &Vs[wseg * 512]);
        }
        __syncthreads();   // drains vmcnt before barrier

        char* const Pb = (char*)&Pl[wave][0][0];
        #pragma unroll
        for (int t = 0; t < 4; ++t) {
            const bf16x8 ak0 = *(const bf16x8*)&Ks[(t * 16 + r15) * 64 + ((quad ^ (r15 & 7)) * 8)];
            const bf16x8 ak1 = *(const bf16x8*)&Ks[(t * 16 + r15) * 64 + (((4 + quad) ^ (r15 & 7)) * 8)];
            const float4 m4 = *(const float4*)(mb + kb + t * 16 + quad * 4);
            #pragma unroll
            for (int qf = 0; qf < 2; ++qf) {
                f32x4 z = {};
                z = __builtin_amdgcn_mfma_f32_16x16x32_bf16(ak0, bq[qf][0], z, 0, 0, 0);
                z = __builtin_amdgcn_mfma_f32_16x16x32_bf16(ak1, bq[qf][1], z, 0, 0, 0);
                // z = S^T (already in log2 domain): lane holds (key=t*16+quad*4+r, query=r15)
                const float p0 = EXP2F(z[0] + m4.x);
                const float p1 = EXP2F(z[1] + m4.y);
                const float p2 = EXP2F(z[2] + m4.z);
                const float p3 = EXP2F(z[3] + m4.w);
                l_part[qf] += (p0 + p1) + (p2 + p3);
                uint2 pw;
                pw.x = pack_bf16(p0, p1);
                pw.y = pack_bf16(p2, p3);
                const int c2 = (t * 2 + (quad >> 1)) ^ (r15 & 7);
                *(uint2*)(Pb + qf * 2048 + r15 * 128 + c2 * 16 + (quad & 1) * 8) = pw;
            }
        }
        asm volatile("s_waitcnt lgkmcnt(0)" ::: "memory");

        #pragma unroll
        for (int u = 0; u < 2; ++u) {
            const int cs = ((u * 4 + quad) ^ (r15 & 7)) * 8;
            bf16x8 vf[4];
            #pragma unroll
            for (int nt = 0; nt < 4; ++nt)
                vf[nt] = *(const bf16x8*)&Vs[(nt * 16 + r15) * 64 + cs];
            #pragma unroll
            for (int qf = 0; qf < 2; ++qf) {
                const bf16x8 ap = *(const bf16x8*)(Pb + qf * 2048 + r15 * 128 + cs * 2);
                #pragma unroll
                for (int nt = 0; nt < 4; ++nt)
                    oacc[qf][nt] = __builtin_amdgcn_mfma_f32_16x16x32_bf16(
                        ap, vf[nt], oacc[qf][nt], 0, 0, 0);
            }
        }
    }

    #pragma unroll
    for (int qf = 0; qf < 2; ++qf) {
        float l = l_part[qf];
        l += __shfl_xor(l, 16);
        l += __shfl_xor(l, 32);      // now: l for query r15 (within fragment qf)
        float lq[4];
        #pragma unroll
        for (int r = 0; r < 4; ++r) lq[r] = __shfl(l, quad * 4 + r, 64);
        #pragma unroll
        for (int nt = 0; nt < 4; ++nt) {
            #pragma unroll
            for (int r = 0; r < 4; ++r) {
                const int row = q0 + qf * 16 + quad * 4 + r;
                const int col = h * DK + nt * 16 + r15;
                Oa[((size_t)b * SEQ + row) * DMODEL + col] = f2bf(oacc[qf][nt][r] / lq[r]);
            }
        }
    }
}

extern "C" void kernel_launch(void* const* d_in, const int* in_sizes, int n_in,
                              void* d_out, int out_size, void* d_ws, size_t ws_size,
                              hipStream_t stream) {
    (void)in_sizes; (void)n_in; (void)out_size; (void)ws_size;
    const float* x  = (const float*)d_in[0];
    const int* mask = (const int*)d_in[1];
    const float* Wq = (const float*)d_in[2];
    const float* bq = (const float*)d_in[3];
    const float* Wk = (const float*)d_in[4];
    const float* bk = (const float*)d_in[5];
    const float* Wv = (const float*)d_in[6];
    const float* bv = (const float*)d_in[7];
    const float* Wo = (const float*)d_in[8];
    const float* bo = (const float*)d_in[9];
    float* out = (float*)d_out;

    char* ws = (char*)d_ws;
    unsigned short* xb  = (unsigned short*)(ws);                                   // 8192x1024 bf16
    unsigned short* wqb = (unsigned short*)(ws + 16777216);                        // 1024x1024 bf16
    unsigned short* wkb = (unsigned short*)(ws + 16777216 + 1 * 2097152);
    unsigned short* wvb = (unsigned short*)(ws + 16777216 + 2 * 2097152);
    unsigned short* wob = (unsigned short*)(ws + 16777216 + 3 * 2097152);
    unsigned short* qb  = (unsigned short*)(ws + 16777216 + 4 * 2097152);          // [BH,L,64]
    unsigned short* kb  = qb  + (size_t)MROWS * DMODEL;                            // [BH,L,64]
    unsigned short* vtb = kb  + (size_t)MROWS * DMODEL;                            // blocked V
    unsigned short* ab  = vtb + (size_t)MROWS * DMODEL;                            // [B,L,DMODEL]
    float*          mbf = (float*)(ab + (size_t)MROWS * DMODEL);                   // [B,L]

    cvt_kernel<<<dim3(MROWS * DMODEL / 4 / 256), 256, 0, stream>>>(x, xb, MROWS * DMODEL / 4);
    cvtw_kernel<<<dim3(DMODEL * DMODEL / 4 / 256, 4), 256, 0, stream>>>(
        Wq, Wk, Wv, Wo, wqb, wkb, wvb, wob);
    maskbias_kernel<<<dim3(BATCH * SEQ / 256), 256, 0, stream>>>(mask, mbf, BATCH * SEQ);

    // fused QKV: grid.x = 3 weights x 8 n-tiles
    gemm128<0><<<dim3(24, MROWS / 128), 256, 0, stream>>>(
        xb, wqb, wkb, wvb, bq, bk, bv, qb, kb, vtb);

    flash_attn<<<dim3(16, BATCH * NHEADS), 256, 0, stream>>>(qb, kb, vtb, mbf, ab);

    gemm128<1><<<dim3(8, MROWS / 128), 256, 0, stream>>>(
        ab, wob, nullptr, nullptr, bo, nullptr, nullptr, out, nullptr, nullptr);
}